// Round 3
// baseline (352.335 us; speedup 1.0000x reference)
//
#include <hip/hip_runtime.h>
#include <cmath>

typedef unsigned int uint;

constexpr int N  = 131072;    // nodes
constexpr int E  = 4194304;   // edges (without self-loops)
constexpr int F  = 16;        // hidden width H1
constexpr int NB = 512;       // dst buckets of 256 nodes == grid size
constexpr int T  = 512;       // threads per block (8 waves)
constexpr int CHUNK = 8192;   // edges per scatter chunk (NB*CHUNK == E)
constexpr int EPT   = 16;     // edges per thread in scatter phase
constexpr int CAPB  = 9216;   // per-bucket LDS stage capacity (mean 8192, sd ~90, 11 sigma)
constexpr uint SENT = 0xFFFFFFFFu;

// Fixed-point scales for native int LDS atomics (float LDS atomicAdd is a
// CAS loop on gfx9; int ds_add is native — verified in the earlier session).
constexpr float S1 = 4194304.0f;    // 2^22 for layer-1 sums (|y|<1, deg<=~64)
constexpr float S2 = 65536.0f;      // 2^16 for layer-2 sums (|g2| small)

// Manual device-scope grid barrier (regular launch; no hipLaunchCooperativeKernel,
// whose error return the harness can't surface — round-2 post-mortem showed the
// coop launch was rejected and the kernel never ran).
// Safety: co-residency is guaranteed by construction — __launch_bounds__(512,4)
// caps VGPR at 128 (4 waves/SIMD), LDS is 60KB/block -> exactly 2 blocks/CU,
// grid = 2*256. Spin is bounded so a mistake fails the check instead of hanging.
__device__ __forceinline__ void gsync(uint* cnt, uint* rel, int t, uint gen) {
    __syncthreads();
    if (t == 0) {
        __threadfence();                              // release this block's stores
        uint v = __hip_atomic_fetch_add(cnt, 1u, __ATOMIC_ACQ_REL,
                                        __HIP_MEMORY_SCOPE_AGENT);
        if (v == (uint)(NB - 1)) {                    // last arriver
            __hip_atomic_store(cnt, 0u, __ATOMIC_RELAXED, __HIP_MEMORY_SCOPE_AGENT);
            __hip_atomic_store(rel, gen, __ATOMIC_RELEASE, __HIP_MEMORY_SCOPE_AGENT);
        } else {
            int guard = 0;
            while (__hip_atomic_load(rel, __ATOMIC_ACQUIRE,
                                     __HIP_MEMORY_SCOPE_AGENT) < gen) {
                __builtin_amdgcn_s_sleep(2);
                if (++guard > (1 << 22)) break;       // ~0.2s cap: fail, don't hang
            }
        }
        __threadfence();                              // acquire others' stores
    }
    __syncthreads();
}

// ws is poisoned between timing iterations -> barrier state must be re-zeroed
// by a tiny kernel before each fused run (graph replays both).
__global__ void k_init(uint* bar) {
    if (threadIdx.x < 64) bar[threadIdx.x] = 0;
}

// One fused kernel: scatter -> gather-to-LDS -> l1 -> l2 -> out, separated by
// manual grid barriers. The bucket edge list lives in LDS (stage[]) from the
// gather phase through both layer passes — no part2 global round-trip.
__global__ void __launch_bounds__(T, 4) k_fused(
        const int* __restrict__ src, const int* __restrict__ dst,
        const float* __restrict__ x,
        const float* __restrict__ W1, const float* __restrict__ b1,
        const float* __restrict__ W2, const float* __restrict__ b2,
        uint* __restrict__ dirw, float2* __restrict__ y,
        float* __restrict__ g2, float* __restrict__ scores,
        uint* bar,
        uint* part_out /* part (phases 0-2) then out (phase 7); aliases d_out */) {
    __shared__ uint stage[CAPB];        // 36 KB: scatter vals, then bucket edges
    __shared__ uint ps[NB + 1];         // hist/bump (ph0), run-prefix (ph2+)
    __shared__ uint segoff[NB];         // run offsets in part
    __shared__ int  bins0[8 * 256];     // wave-private bins: deg / a0 / l2
    __shared__ int  bins1[8 * 256];     // wave-private bins: a1
    __shared__ float  dl[256];          // own dinv
    __shared__ float2 yl[256];          // own y
    __shared__ float  g2l[256];         // own g2
    __shared__ uint wsum[8];

    int t = threadIdx.x, g = blockIdx.x;
    int lane = t & 63, w = t >> 6;
    uint* part = part_out;
    uint* cnt = bar;                    // bar[0]
    uint* rel = bar + 32;               // separate cacheline

    // ---------------- Phase 0: scatter (block-local bucket grouping) --------
    ps[t] = 0;                                    // h[t]
    __syncthreads();
    int d[EPT], s[EPT];
    {
        const int4* src4 = (const int4*)src;
        const int4* dst4 = (const int4*)dst;
        int base4 = g * (CHUNK / 4);
#pragma unroll
        for (int k = 0; k < EPT / 4; ++k) {
            int4 d4 = dst4[base4 + k * T + t];
            int4 s4 = src4[base4 + k * T + t];
            d[4 * k + 0] = d4.x; d[4 * k + 1] = d4.y; d[4 * k + 2] = d4.z; d[4 * k + 3] = d4.w;
            s[4 * k + 0] = s4.x; s[4 * k + 1] = s4.y; s[4 * k + 2] = s4.z; s[4 * k + 3] = s4.w;
            atomicAdd(&ps[d4.x >> 8], 1u);
            atomicAdd(&ps[d4.y >> 8], 1u);
            atomicAdd(&ps[d4.z >> 8], 1u);
            atomicAdd(&ps[d4.w >> 8], 1u);
        }
    }
    __syncthreads();
    {
        uint v = ps[t];
        uint sv = v;                              // wave inclusive scan
#pragma unroll
        for (int off = 1; off < 64; off <<= 1) {
            uint n = __shfl_up(sv, off);
            if (lane >= off) sv += n;
        }
        if (lane == 63) wsum[w] = sv;
        __syncthreads();
        uint wo = 0;
        for (int i = 0; i < w; ++i) wo += wsum[i];
        sv += wo;
        uint ex = sv - v;                         // local exclusive offset
        dirw[(size_t)g * NB + t] = v | (ex << 16);
        __syncthreads();
        ps[t] = ex;                               // bump counters
        __syncthreads();
#pragma unroll
        for (int k = 0; k < EPT; ++k) {
            int b = d[k] >> 8;
            uint slot = atomicAdd(&ps[b], 1u);
            stage[slot] = ((uint)s[k] << 8) | (uint)(d[k] & 255);
        }
        __syncthreads();
        uint4* part4 = (uint4*)(part + (size_t)g * CHUNK);
        const uint4* st4 = (const uint4*)stage;
#pragma unroll
        for (int k = 0; k < EPT / 4; ++k)         // coalesced 16B stores
            part4[k * T + t] = st4[k * T + t];
    }
    gsync(cnt, rel, t, 1);

    // ---------------- Phase 2: gather bucket edges into LDS -----------------
#pragma unroll
    for (int k = 0; k < 4; ++k) bins0[k * T + t] = 0;   // degree bins
    {
        uint pd = dirw[(size_t)t * NB + g];       // column read (t indexes chunk)
        uint len = pd & 0xFFFFu;
        segoff[t] = (uint)t * CHUNK + (pd >> 16);
        uint sv = len;
#pragma unroll
        for (int off = 1; off < 64; off <<= 1) {
            uint n = __shfl_up(sv, off);
            if (lane >= off) sv += n;
        }
        if (lane == 63) wsum[w] = sv;
        uint part_ps = sv - len;
        __syncthreads();                          // wsum ready; bins zeroed
        uint wo = 0;
        for (int i = 0; i < w; ++i) wo += wsum[i];
        ps[t] = part_ps + wo;
        if (t == 0) {
            uint Lt = 0;
#pragma unroll
            for (int i = 0; i < 8; ++i) Lt += wsum[i];
            ps[NB] = Lt;
        }
    }
    __syncthreads();
    uint L  = ps[NB];
    uint Lc = (L > (uint)CAPB) ? (uint)CAPB : L;
    uint Lp = (Lc + 3u) & ~3u;                    // pad to x4 for uint4 readers
    {
        int sub = lane >> 4, l16 = lane & 15;     // 4 runs per wave
#pragma unroll 2
        for (int pass = 0; pass < 16; ++pass) {   // 8 waves * 4 * 16 = 512 runs
            int r = pass * 32 + w * 4 + sub;
            uint off = segoff[r], base = ps[r], len = ps[r + 1] - base;
            for (uint j = l16; j < len; j += 16) {
                uint pk = part[off + j];
                atomicAdd((uint*)&bins0[w * 256 + (pk & 255u)], 1u);
                if (base + j < (uint)CAPB) stage[base + j] = pk;
            }
        }
        uint i2 = Lc + (uint)t;
        if (i2 < Lp) stage[i2] = SENT;            // <=3 sentinel pads
    }
    __syncthreads();
    if (t < 256) {
        uint c = 0;
#pragma unroll
        for (int k = 0; k < 8; ++k) c += (uint)bins0[k * 256 + t];
        int node = (g << 8) + t;
        float di = rsqrtf(1.0f + (float)c);       // +1 self-loop
        dl[t] = di;
        float2 xv = ((const float2*)x)[node];
        float2 yv = make_float2(di * xv.x, di * xv.y);
        yl[t] = yv;
        y[node] = yv;                             // needed cross-block in l1
    }
    gsync(cnt, rel, t, 2);

    // ---------------- Phase 4: layer 1 (stream LDS stage, fused MLP) --------
#pragma unroll
    for (int k = 0; k < 4; ++k) { bins0[k * T + t] = 0; bins1[k * T + t] = 0; }
    __syncthreads();
    uint L4 = Lp >> 2;
    {
        const uint4* st4 = (const uint4*)stage;
        for (uint i = t; i < L4; i += T) {
            uint4 q = st4[i];
            bool v0 = q.x != SENT, v1 = q.y != SENT, v2 = q.z != SENT, v3 = q.w != SENT;
            float2 y0, y1, y2, y3;                // issue all gathers first
            if (v0) y0 = y[q.x >> 8];
            if (v1) y1 = y[q.y >> 8];
            if (v2) y2 = y[q.z >> 8];
            if (v3) y3 = y[q.w >> 8];
            if (v0) { atomicAdd(&bins0[w * 256 + (q.x & 255u)], __float2int_rn(y0.x * S1));
                      atomicAdd(&bins1[w * 256 + (q.x & 255u)], __float2int_rn(y0.y * S1)); }
            if (v1) { atomicAdd(&bins0[w * 256 + (q.y & 255u)], __float2int_rn(y1.x * S1));
                      atomicAdd(&bins1[w * 256 + (q.y & 255u)], __float2int_rn(y1.y * S1)); }
            if (v2) { atomicAdd(&bins0[w * 256 + (q.z & 255u)], __float2int_rn(y2.x * S1));
                      atomicAdd(&bins1[w * 256 + (q.z & 255u)], __float2int_rn(y2.y * S1)); }
            if (v3) { atomicAdd(&bins0[w * 256 + (q.w & 255u)], __float2int_rn(y3.x * S1));
                      atomicAdd(&bins1[w * 256 + (q.w & 255u)], __float2int_rn(y3.y * S1)); }
        }
    }
    __syncthreads();
    if (t < 256) {
        int s0 = 0, s1 = 0;
#pragma unroll
        for (int k = 0; k < 8; ++k) { s0 += bins0[k * 256 + t]; s1 += bins1[k * 256 + t]; }
        int node = (g << 8) + t;
        float di = dl[t];
        float2 yn = yl[t];
        float A0 = di * ((float)s0 * (1.0f / S1) + yn.x);   // + self-loop
        float A1 = di * ((float)s1 * (1.0f / S1) + yn.y);
        float acc = 0.0f;
#pragma unroll
        for (int f = 0; f < F; ++f) {
            float v = fmaf(A0, W1[f], fmaf(A1, W1[F + f], b1[f]));
            acc = fmaf(fmaxf(v, 0.0f), W2[f], acc);
        }
        float gg = di * acc;
        g2l[t] = gg;
        g2[node] = gg;                            // needed cross-block in l2
    }
    gsync(cnt, rel, t, 3);

    // ---------------- Phase 5: layer 2 (stream LDS stage, sigmoid) ----------
#pragma unroll
    for (int k = 0; k < 4; ++k) bins0[k * T + t] = 0;
    __syncthreads();
    {
        uint L4b = Lp >> 2;
        const uint4* st4 = (const uint4*)stage;
        for (uint i = t; i < L4b; i += T) {
            uint4 q = st4[i];
            uint pk;
#pragma unroll
            for (int k = 0; k < 4; ++k) {
                pk = (k == 0) ? q.x : (k == 1) ? q.y : (k == 2) ? q.z : q.w;
                if (pk != SENT)
                    atomicAdd(&bins0[w * 256 + (pk & 255u)], __float2int_rn(g2[pk >> 8] * S2));
            }
        }
    }
    __syncthreads();
    if (t < 256) {
        int sacc = 0;
#pragma unroll
        for (int k = 0; k < 8; ++k) sacc += bins0[k * 256 + t];
        int node = (g << 8) + t;
        float acc = (float)sacc * (1.0f / S2);
        float v = fmaf(dl[t], acc + g2l[t], b2[0]);
        scores[node] = 1.0f / (1.0f + expf(-v));
    }
    gsync(cnt, rel, t, 4);

    // ---------------- Phase 7: out[e] = scores[src[e]] ----------------------
    {
        const int4* s4p = (const int4*)src;
        float4* o4 = (float4*)part_out;           // part is dead; reuse as out
        for (int i = g * T + t; i < E / 4; i += NB * T) {
            int4 s4 = s4p[i];
            float4 o;
            o.x = scores[s4.x];
            o.y = scores[s4.y];
            o.z = scores[s4.z];
            o.w = scores[s4.w];
            o4[i] = o;
        }
    }
}

extern "C" void kernel_launch(void* const* d_in, const int* in_sizes, int n_in,
                              void* d_out, int out_size, void* d_ws, size_t ws_size,
                              hipStream_t stream) {
    const float* x  = (const float*)d_in[0];   // [N,2]
    const float* W1 = (const float*)d_in[1];   // [2,16]
    const float* b1 = (const float*)d_in[2];   // [16]
    const float* W2 = (const float*)d_in[3];   // [16,1]
    const float* b2 = (const float*)d_in[4];   // [1]
    const int*   ei = (const int*)d_in[5];     // [2,E]
    const int* src = ei;
    const int* dst = ei + E;

    // ws: dirw[512*512 u32] | y[N f32x2] | g2[N] | scores[N] | bar[64]  (~3 MB)
    uint*   dirw   = (uint*)d_ws;
    float2* y      = (float2*)(dirw + (size_t)NB * NB);
    float*  g2     = (float*)(y + N);
    float*  scores = g2 + N;
    uint*   bar    = (uint*)(scores + N);
    uint*   part_out = (uint*)d_out;           // part (phases 0-2), out (phase 7)

    k_init <<<1, 64, 0, stream>>>(bar);
    k_fused<<<NB, T, 0, stream>>>(src, dst, x, W1, b1, W2, b2,
                                  dirw, y, g2, scores, bar, part_out);
}

// Round 4
// 169.178 us; speedup vs baseline: 2.0826x; 2.0826x over previous
//
#include <hip/hip_runtime.h>
#include <cmath>

typedef unsigned int uint;

constexpr int N  = 131072;    // nodes
constexpr int E  = 4194304;   // edges (without self-loops)
constexpr int F  = 16;        // hidden width H1
constexpr int NB = 512;       // dst buckets of 256 nodes (bucket = dst>>8)
constexpr int NBLK  = 512;    // scatter blocks
constexpr int SCT   = 512;    // threads per scatter block
constexpr int CHUNK = 8192;   // edges per scatter block (NBLK*CHUNK == E)
constexpr int EPT   = 16;     // edges per thread in scatter
constexpr int CAPB  = 9216;   // per-bucket region (mean 8192, sd ~90 -> 11 sigma)
constexpr int LT    = 1024;   // threads per dy/l1/l2 block (16 waves)
constexpr uint SENT = 0xFFFFFFFFu;   // pad sentinel edge

// Fixed-point scales for native int LDS atomics (float LDS atomicAdd is a
// CAS loop on gfx9; int ds_add is native — verified in the earlier session).
constexpr float S1 = 4194304.0f;    // 2^22 for layer-1 sums (|y|<1, deg<=~64)
constexpr float S2 = 65536.0f;      // 2^16 for layer-2 sums (|g2| small)

// gcnt (per-bucket global bump counters) must be zero at scatter time; ws is
// poisoned between timing iterations, so a tiny init kernel re-zeroes it.
__global__ void k_init(uint* gcnt) {
    gcnt[threadIdx.x] = 0;
}

// ---- Pass 1: scatter DIRECTLY into bucket-contiguous part2 -----------------
// Block-local grouping (verified round-1 logic), then one global atomicAdd per
// bucket reserves a disjoint span in that bucket's region; the block's runs
// are written straight there (64B-run scattered writes). Eliminates the
// part->gather->part2 round-trip (saves ~34 MB traffic + a whole pass).
__global__ void __launch_bounds__(SCT) k_scatter(
        const int* __restrict__ src, const int* __restrict__ dst,
        uint* __restrict__ gcnt, uint* __restrict__ part2) {
    __shared__ uint ps[NB];         // hist -> bump counters -> run ends
    __shared__ uint gbase[NB];      // this block's reserved base per bucket
    __shared__ uint vals[CHUNK];    // 32 KB staging
    __shared__ uint wsum[8];
    int t = threadIdx.x, g = blockIdx.x;
    int lane = t & 63, w = t >> 6;
    ps[t] = 0;
    __syncthreads();
    int d[EPT], s[EPT];
    const int4* src4 = (const int4*)src;
    const int4* dst4 = (const int4*)dst;
    int base4 = g * (CHUNK / 4);
#pragma unroll
    for (int k = 0; k < EPT / 4; ++k) {
        int4 d4 = dst4[base4 + k * SCT + t];
        int4 s4 = src4[base4 + k * SCT + t];
        d[4 * k + 0] = d4.x; d[4 * k + 1] = d4.y; d[4 * k + 2] = d4.z; d[4 * k + 3] = d4.w;
        s[4 * k + 0] = s4.x; s[4 * k + 1] = s4.y; s[4 * k + 2] = s4.z; s[4 * k + 3] = s4.w;
        atomicAdd(&ps[d4.x >> 8], 1u);
        atomicAdd(&ps[d4.y >> 8], 1u);
        atomicAdd(&ps[d4.z >> 8], 1u);
        atomicAdd(&ps[d4.w >> 8], 1u);
    }
    __syncthreads();
    uint v = ps[t];
    uint sv = v;                                  // wave inclusive scan
#pragma unroll
    for (int off = 1; off < 64; off <<= 1) {
        uint n = __shfl_up(sv, off);
        if (lane >= off) sv += n;
    }
    if (lane == 63) wsum[w] = sv;
    gbase[t] = atomicAdd(&gcnt[t], v);            // reserve span in bucket t
    __syncthreads();
    uint wo = 0;
    for (int i = 0; i < w; ++i) wo += wsum[i];
    sv += wo;                                     // inclusive over 512 buckets
    uint ex = sv - v;                             // local exclusive offset
    __syncthreads();                              // all reads of ps done
    ps[t] = ex;                                   // bump starts at excl
    __syncthreads();
#pragma unroll
    for (int k = 0; k < EPT; ++k) {
        int b = d[k] >> 8;
        uint slot = atomicAdd(&ps[b], 1u);
        vals[slot] = ((uint)s[k] << 8) | (uint)(d[k] & 255);
    }
    __syncthreads();                              // ps[b] now = run END of b
    // run-walk write: 16-lane groups, 4 runs per wave, 16 passes = 512 runs
    int sub = lane >> 4, l16 = lane & 15;
#pragma unroll 2
    for (int pass = 0; pass < 16; ++pass) {
        int r = pass * 32 + w * 4 + sub;
        uint end = ps[r];
        uint beg = (r == 0) ? 0u : ps[r - 1];
        uint len = end - beg;
        uint gb = gbase[r];
        uint* o = part2 + (size_t)r * CAPB;
        for (uint j = l16; j < len; j += 16) {
            uint gi = gb + j;
            if (gi < (uint)CAPB) o[gi] = vals[beg + j];
        }
    }
}

// ---- Pass 2: degrees + dinv + y (stream part2 once, LDS count bins) --------
__global__ void __launch_bounds__(LT) k_dy(
        uint* __restrict__ part2, const uint* __restrict__ gcnt,
        const float* __restrict__ x,
        uint* __restrict__ blen, float* __restrict__ dinv, float2* __restrict__ y) {
    __shared__ uint cw[16 * 256];   // wave-private count bins (16 KB)
    int t = threadIdx.x, b = blockIdx.x, w = t >> 6;
#pragma unroll
    for (int k = 0; k < 4; ++k) cw[k * LT + t] = 0;
    __syncthreads();
    uint L  = gcnt[b];
    uint Lc = (L > (uint)CAPB) ? (uint)CAPB : L;
    uint Lp = (Lc + 3u) & ~3u;
    uint* p = part2 + (size_t)b * CAPB;
    uint L4 = Lc >> 2;
    const uint4* p4 = (const uint4*)p;
    for (uint i = t; i < L4; i += LT) {
        uint4 q = p4[i];
        atomicAdd(&cw[w * 256 + (q.x & 255u)], 1u);
        atomicAdd(&cw[w * 256 + (q.y & 255u)], 1u);
        atomicAdd(&cw[w * 256 + (q.z & 255u)], 1u);
        atomicAdd(&cw[w * 256 + (q.w & 255u)], 1u);
    }
    uint it = (L4 << 2) + (uint)t;                // tail (<=3 edges)
    if (it < Lc) atomicAdd(&cw[w * 256 + (p[it] & 255u)], 1u);
    uint i2 = Lc + (uint)t;
    if (i2 < Lp) p[i2] = SENT;                    // <=3 sentinel pads
    if (t == 0) blen[b] = Lp;
    __syncthreads();
    if (t < 256) {
        uint c = 0;
#pragma unroll
        for (int k = 0; k < 16; ++k) c += cw[k * 256 + t];
        int node = (b << 8) + t;
        float di = rsqrtf(1.0f + (float)c);       // +1 self-loop
        dinv[node] = di;
        float2 xv = ((const float2*)x)[node];
        y[node] = make_float2(di * xv.x, di * xv.y);
    }
}

// ---- Pass 3: layer 1 — uint4 stream (1-ahead prefetch), int LDS bins + MLP -
__global__ void __launch_bounds__(LT) k_l1(
        const uint* __restrict__ part2, const uint* __restrict__ blen,
        const float2* __restrict__ y, const float* __restrict__ dinv,
        const float* __restrict__ W1, const float* __restrict__ b1,
        const float* __restrict__ W2, float* __restrict__ g2) {
    __shared__ int a0[16 * 256], a1[16 * 256];    // 32 KB, wave-private
    int t = threadIdx.x, b = blockIdx.x, w = t >> 6;
#pragma unroll
    for (int k = 0; k < 4; ++k) { a0[k * LT + t] = 0; a1[k * LT + t] = 0; }
    __syncthreads();
    uint L4 = blen[b] >> 2;
    const uint4* p4 = (const uint4*)(part2 + (size_t)b * CAPB);
    uint i = t;
    uint4 q = (i < L4) ? p4[i] : make_uint4(SENT, SENT, SENT, SENT);
    while (i < L4) {
        uint in = i + LT;                         // prefetch next iteration
        uint4 qn = (in < L4) ? p4[in] : make_uint4(SENT, SENT, SENT, SENT);
        bool v0 = q.x != SENT, v1 = q.y != SENT, v2 = q.z != SENT, v3 = q.w != SENT;
        float2 y0, y1, y2, y3;                    // issue all gathers first
        if (v0) y0 = y[q.x >> 8];
        if (v1) y1 = y[q.y >> 8];
        if (v2) y2 = y[q.z >> 8];
        if (v3) y3 = y[q.w >> 8];
        if (v0) { atomicAdd(&a0[w * 256 + (q.x & 255u)], __float2int_rn(y0.x * S1));
                  atomicAdd(&a1[w * 256 + (q.x & 255u)], __float2int_rn(y0.y * S1)); }
        if (v1) { atomicAdd(&a0[w * 256 + (q.y & 255u)], __float2int_rn(y1.x * S1));
                  atomicAdd(&a1[w * 256 + (q.y & 255u)], __float2int_rn(y1.y * S1)); }
        if (v2) { atomicAdd(&a0[w * 256 + (q.z & 255u)], __float2int_rn(y2.x * S1));
                  atomicAdd(&a1[w * 256 + (q.z & 255u)], __float2int_rn(y2.y * S1)); }
        if (v3) { atomicAdd(&a0[w * 256 + (q.w & 255u)], __float2int_rn(y3.x * S1));
                  atomicAdd(&a1[w * 256 + (q.w & 255u)], __float2int_rn(y3.y * S1)); }
        q = qn; i = in;
    }
    __syncthreads();
    if (t < 256) {
        int s0 = 0, s1 = 0;
#pragma unroll
        for (int k = 0; k < 16; ++k) { s0 += a0[k * 256 + t]; s1 += a1[k * 256 + t]; }
        int node = (b << 8) + t;
        float di = dinv[node];
        float2 yn = y[node];
        float A0 = di * ((float)s0 * (1.0f / S1) + yn.x);   // + self-loop
        float A1 = di * ((float)s1 * (1.0f / S1) + yn.y);
        float acc = 0.0f;
#pragma unroll
        for (int f = 0; f < F; ++f) {
            float v = fmaf(A0, W1[f], fmaf(A1, W1[F + f], b1[f]));
            acc = fmaf(fmaxf(v, 0.0f), W2[f], acc);
        }
        g2[node] = di * acc;
    }
}

// ---- Pass 4: layer 2 — uint4 stream (prefetch), int LDS bins + sigmoid -----
__global__ void __launch_bounds__(LT) k_l2(
        const uint* __restrict__ part2, const uint* __restrict__ blen,
        const float* __restrict__ g2, const float* __restrict__ dinv,
        const float* __restrict__ b2, float* __restrict__ scores) {
    __shared__ int a[16 * 256];                   // 16 KB, wave-private
    int t = threadIdx.x, b = blockIdx.x, w = t >> 6;
#pragma unroll
    for (int k = 0; k < 4; ++k) a[k * LT + t] = 0;
    __syncthreads();
    uint L4 = blen[b] >> 2;
    const uint4* p4 = (const uint4*)(part2 + (size_t)b * CAPB);
    uint i = t;
    uint4 q = (i < L4) ? p4[i] : make_uint4(SENT, SENT, SENT, SENT);
    while (i < L4) {
        uint in = i + LT;
        uint4 qn = (in < L4) ? p4[in] : make_uint4(SENT, SENT, SENT, SENT);
        bool v0 = q.x != SENT, v1 = q.y != SENT, v2 = q.z != SENT, v3 = q.w != SENT;
        float f0, f1, f2, f3;
        if (v0) f0 = g2[q.x >> 8];
        if (v1) f1 = g2[q.y >> 8];
        if (v2) f2 = g2[q.z >> 8];
        if (v3) f3 = g2[q.w >> 8];
        if (v0) atomicAdd(&a[w * 256 + (q.x & 255u)], __float2int_rn(f0 * S2));
        if (v1) atomicAdd(&a[w * 256 + (q.y & 255u)], __float2int_rn(f1 * S2));
        if (v2) atomicAdd(&a[w * 256 + (q.z & 255u)], __float2int_rn(f2 * S2));
        if (v3) atomicAdd(&a[w * 256 + (q.w & 255u)], __float2int_rn(f3 * S2));
        q = qn; i = in;
    }
    __syncthreads();
    if (t < 256) {
        int s = 0;
#pragma unroll
        for (int k = 0; k < 16; ++k) s += a[k * 256 + t];
        int node = (b << 8) + t;
        float acc = (float)s * (1.0f / S2);
        float v = fmaf(dinv[node], acc + g2[node], b2[0]);
        scores[node] = 1.0f / (1.0f + expf(-v));
    }
}

// ---- output gather: out[e] = scores[src[e]], 4 edges/thread ----------------
__global__ void k_out(const int* __restrict__ src, const float* __restrict__ scores,
                      float* __restrict__ out) {
    int i = blockIdx.x * blockDim.x + threadIdx.x;
    if (i >= E / 4) return;
    int4 s4 = ((const int4*)src)[i];
    float4 o;
    o.x = scores[s4.x];
    o.y = scores[s4.y];
    o.z = scores[s4.z];
    o.w = scores[s4.w];
    ((float4*)out)[i] = o;
}

extern "C" void kernel_launch(void* const* d_in, const int* in_sizes, int n_in,
                              void* d_out, int out_size, void* d_ws, size_t ws_size,
                              hipStream_t stream) {
    const float* x  = (const float*)d_in[0];   // [N,2]
    const float* W1 = (const float*)d_in[1];   // [2,16]
    const float* b1 = (const float*)d_in[2];   // [16]
    const float* W2 = (const float*)d_in[3];   // [16,1]
    const float* b2 = (const float*)d_in[4];   // [1]
    const int*   ei = (const int*)d_in[5];     // [2,E]
    const int* src = ei;
    const int* dst = ei + E;

    // ws: gcnt[NB] | blen[NB] | dinv[N] | y[N f32x2] | g2[N] | scores[N] |
    //     part2[NB*CAPB u32]   (~21 MB)
    uint*   gcnt   = (uint*)d_ws;
    uint*   blen   = gcnt + NB;
    float*  dinv   = (float*)(blen + NB);
    float2* y      = (float2*)(dinv + N);
    float*  g2     = (float*)(y + N);
    float*  scores = g2 + N;
    uint*   part2  = (uint*)(scores + N);
    float*  out    = (float*)d_out;

    k_init   <<<1,             NB,  0, stream>>>(gcnt);
    k_scatter<<<NBLK,          SCT, 0, stream>>>(src, dst, gcnt, part2);
    k_dy     <<<NB,            LT,  0, stream>>>(part2, gcnt, x, blen, dinv, y);
    k_l1     <<<NB,            LT,  0, stream>>>(part2, blen, y, dinv, W1, b1, W2, g2);
    k_l2     <<<NB,            LT,  0, stream>>>(part2, blen, g2, dinv, b2, scores);
    k_out    <<<E / 4 / 256,   256, 0, stream>>>(src, scores, out);
}